// Round 1
// baseline (3722.426 us; speedup 1.0000x reference)
//
#include <hip/hip_runtime.h>
#include <math.h>

#define HID 128
#define NHEADS 8
#define DH 16
#define EDGE_D 32
#define ETILE 16

// ---------- helpers ----------
static __device__ __forceinline__ float wave_allreduce_sum(float v) {
#pragma unroll
  for (int off = 32; off > 0; off >>= 1) v += __shfl_xor(v, off);
  return v;
}

static __device__ __forceinline__ unsigned enc_f(float f) {
  unsigned u = __float_as_uint(f);
  return (u & 0x80000000u) ? ~u : (u | 0x80000000u);
}
static __device__ __forceinline__ float dec_f(unsigned e) {
  unsigned u = (e & 0x80000000u) ? (e & 0x7fffffffu) : ~e;
  return __uint_as_float(u);
}

// ---------- LayerNorm: out = LN(in) ----------
__global__ __launch_bounds__(256) void ln_kernel(const float* __restrict__ in,
                                                 float* __restrict__ out,
                                                 const float* __restrict__ w,
                                                 const float* __restrict__ b, int n) {
  int wpb = blockDim.x >> 6;
  int row0 = blockIdx.x * wpb + (threadIdx.x >> 6);
  int lane = threadIdx.x & 63;
  int stride = gridDim.x * wpb;
  for (int row = row0; row < n; row += stride) {
    const float* p = in + (size_t)row * HID;
    float a = p[lane], c = p[lane + 64];
    float s = wave_allreduce_sum(a + c);
    float s2 = wave_allreduce_sum(a * a + c * c);
    float mean = s * (1.f / 128.f);
    float var = s2 * (1.f / 128.f) - mean * mean;
    float rs = rsqrtf(var + 1e-5f);
    float* o = out + (size_t)row * HID;
    o[lane] = (a - mean) * rs * w[lane] + b[lane];
    o[lane + 64] = (c - mean) * rs * w[lane + 64] + b[lane + 64];
  }
}

// ---------- finalize conv + LN2: x1 = x + msg/denom + skip ; h2 = LN(x1) ----------
__global__ __launch_bounds__(256) void finalize1_kernel(
    const float* __restrict__ x, const float* __restrict__ msg,
    const float* __restrict__ denom, const float* __restrict__ skip,
    const float* __restrict__ w, const float* __restrict__ b,
    float* __restrict__ x1, float* __restrict__ h2, int n) {
  int wpb = blockDim.x >> 6;
  int row0 = blockIdx.x * wpb + (threadIdx.x >> 6);
  int lane = threadIdx.x & 63;
  int stride = gridDim.x * wpb;
  for (int row = row0; row < n; row += stride) {
    size_t base = (size_t)row * HID;
    float d0 = denom[(size_t)row * NHEADS + (lane >> 4)] + 1e-16f;
    float d1 = denom[(size_t)row * NHEADS + 4 + (lane >> 4)] + 1e-16f;
    float a = x[base + lane] + msg[base + lane] / d0 + skip[base + lane];
    float c = x[base + 64 + lane] + msg[base + 64 + lane] / d1 + skip[base + 64 + lane];
    x1[base + lane] = a;
    x1[base + 64 + lane] = c;
    float s = wave_allreduce_sum(a + c);
    float s2 = wave_allreduce_sum(a * a + c * c);
    float mean = s * (1.f / 128.f);
    float var = s2 * (1.f / 128.f) - mean * mean;
    float rs = rsqrtf(var + 1e-5f);
    h2[base + lane] = (a - mean) * rs * w[lane] + b[lane];
    h2[base + 64 + lane] = (c - mean) * rs * w[lane + 64] + b[lane + 64];
  }
}

// ---------- generic fp32 GEMM: C = act(A@B + bias) (+D) ----------
// A [n,K], B [K,M] row-major, tile 64x128, 256 threads, 4x8 per thread
template <int K, int ACT, int ADDD>
__global__ __launch_bounds__(256) void gemm_kernel(
    const float* __restrict__ A, const float* __restrict__ B,
    const float* __restrict__ bias, const float* __restrict__ D,
    float* __restrict__ C, int n, int M) {
  __shared__ float As[64][33];
  __shared__ float Bs[32][129];
  int r0 = blockIdx.x * 64;
  int c0 = blockIdx.y * 128;
  int t = threadIdx.x;
  int tx = t & 15, ty = t >> 4;
  float acc[4][8];
#pragma unroll
  for (int i = 0; i < 4; i++)
#pragma unroll
    for (int j = 0; j < 8; j++) acc[i][j] = 0.f;

  for (int kc = 0; kc < K; kc += 32) {
    __syncthreads();
#pragma unroll
    for (int i = 0; i < 8; i++) {
      int idx = i * 256 + t;
      int r = idx >> 5, kk = idx & 31;
      int gr = r0 + r;
      As[r][kk] = (gr < n) ? A[(size_t)gr * K + kc + kk] : 0.f;
    }
#pragma unroll
    for (int i = 0; i < 16; i++) {
      int idx = i * 256 + t;
      int kk = idx >> 7, cc = idx & 127;
      Bs[kk][cc] = B[(size_t)(kc + kk) * M + c0 + cc];
    }
    __syncthreads();
#pragma unroll
    for (int kk = 0; kk < 32; kk++) {
      float av[4], bv[8];
#pragma unroll
      for (int i = 0; i < 4; i++) av[i] = As[ty + 16 * i][kk];
#pragma unroll
      for (int j = 0; j < 8; j++) bv[j] = Bs[kk][tx + 16 * j];
#pragma unroll
      for (int i = 0; i < 4; i++)
#pragma unroll
        for (int j = 0; j < 8; j++) acc[i][j] = fmaf(av[i], bv[j], acc[i][j]);
    }
  }
#pragma unroll
  for (int i = 0; i < 4; i++) {
    int r = r0 + ty + 16 * i;
    if (r < n) {
#pragma unroll
      for (int j = 0; j < 8; j++) {
        int c = c0 + tx + 16 * j;
        float val = acc[i][j] + bias[c];
        if (ACT == 1) val = 0.5f * val * (1.f + erff(val * 0.70710678118f));
        if (ADDD) val += D[(size_t)r * M + c];
        C[(size_t)r * M + c] = val;
      }
    }
  }
}

// ---------- edge pass 1: alpha_raw + segment max ----------
__global__ __launch_bounds__(256) void edge_pass1(
    const int* __restrict__ ei, const float* __restrict__ ea,
    const float* __restrict__ We, const float* __restrict__ be,
    const float* __restrict__ q, const float* __restrict__ kmat,
    float* __restrict__ alpha_raw, unsigned* __restrict__ amax_enc, int E) {
  __shared__ float sWe[32][128];
  __shared__ float sBe[128];
  __shared__ float sEa[ETILE][32];
  for (int i = threadIdx.x; i < 32 * 128; i += 256) sWe[i >> 7][i & 127] = We[i];
  if (threadIdx.x < 128) sBe[threadIdx.x] = be[threadIdx.x];
  int ntiles = (E + ETILE - 1) / ETILE;
  int le = threadIdx.x >> 4, l16 = threadIdx.x & 15;
  for (int tile = blockIdx.x; tile < ntiles; tile += gridDim.x) {
    int base = tile * ETILE;
    __syncthreads();
#pragma unroll
    for (int i = 0; i < 2; i++) {
      int idx = i * 256 + threadIdx.x;
      int e = base + (idx >> 5);
      sEa[idx >> 5][idx & 31] = (e < E) ? ea[(size_t)e * 32 + (idx & 31)] : 0.f;
    }
    __syncthreads();
    int e = base + le;
    if (e < E) {
      int src = ei[e];
      int dst = ei[E + e];
      int d0 = l16 * 8;
      float ep[8];
#pragma unroll
      for (int i = 0; i < 8; i++) ep[i] = sBe[d0 + i];
#pragma unroll
      for (int j = 0; j < 32; j++) {
        float a = sEa[le][j];
        const float4* wr = (const float4*)&sWe[j][d0];
        float4 w0 = wr[0], w1 = wr[1];
        ep[0] = fmaf(a, w0.x, ep[0]); ep[1] = fmaf(a, w0.y, ep[1]);
        ep[2] = fmaf(a, w0.z, ep[2]); ep[3] = fmaf(a, w0.w, ep[3]);
        ep[4] = fmaf(a, w1.x, ep[4]); ep[5] = fmaf(a, w1.y, ep[5]);
        ep[6] = fmaf(a, w1.z, ep[6]); ep[7] = fmaf(a, w1.w, ep[7]);
      }
      const float4* qp = (const float4*)(q + (size_t)dst * HID + d0);
      const float4* kp = (const float4*)(kmat + (size_t)src * HID + d0);
      float4 q0 = qp[0], q1 = qp[1], k0 = kp[0], k1 = kp[1];
      float p = q0.x * (k0.x + ep[0]) + q0.y * (k0.y + ep[1]) +
                q0.z * (k0.z + ep[2]) + q0.w * (k0.w + ep[3]) +
                q1.x * (k1.x + ep[4]) + q1.y * (k1.y + ep[5]) +
                q1.z * (k1.z + ep[6]) + q1.w * (k1.w + ep[7]);
      float alpha = (p + __shfl_xor(p, 1)) * 0.25f;  // 1/sqrt(16)
      if (!(l16 & 1)) {
        int hh = l16 >> 1;
        alpha_raw[(size_t)e * NHEADS + hh] = alpha;
        atomicMax(&amax_enc[(size_t)dst * NHEADS + hh], enc_f(alpha));
      }
    }
  }
}

// ---------- edge pass 2: expa, denom, msg scatter ----------
__global__ __launch_bounds__(256) void edge_pass2(
    const int* __restrict__ ei, const float* __restrict__ ea,
    const float* __restrict__ We, const float* __restrict__ be,
    const float* __restrict__ vmat, const float* __restrict__ alpha_raw,
    const unsigned* __restrict__ amax_enc, float* __restrict__ denom,
    float* __restrict__ msg, int E) {
  __shared__ float sWe[32][128];
  __shared__ float sBe[128];
  __shared__ float sEa[ETILE][32];
  for (int i = threadIdx.x; i < 32 * 128; i += 256) sWe[i >> 7][i & 127] = We[i];
  if (threadIdx.x < 128) sBe[threadIdx.x] = be[threadIdx.x];
  int ntiles = (E + ETILE - 1) / ETILE;
  int le = threadIdx.x >> 4, l16 = threadIdx.x & 15;
  for (int tile = blockIdx.x; tile < ntiles; tile += gridDim.x) {
    int base = tile * ETILE;
    __syncthreads();
#pragma unroll
    for (int i = 0; i < 2; i++) {
      int idx = i * 256 + threadIdx.x;
      int e = base + (idx >> 5);
      sEa[idx >> 5][idx & 31] = (e < E) ? ea[(size_t)e * 32 + (idx & 31)] : 0.f;
    }
    __syncthreads();
    int e = base + le;
    if (e < E) {
      int src = ei[e];
      int dst = ei[E + e];
      int hh = l16 >> 1;
      float araw = alpha_raw[(size_t)e * NHEADS + hh];
      float amax = dec_f(amax_enc[(size_t)dst * NHEADS + hh]);
      float expa = expf(araw - amax);
      if (!(l16 & 1)) atomicAdd(&denom[(size_t)dst * NHEADS + hh], expa);
      int d0 = l16 * 8;
      float ep[8];
#pragma unroll
      for (int i = 0; i < 8; i++) ep[i] = sBe[d0 + i];
#pragma unroll
      for (int j = 0; j < 32; j++) {
        float a = sEa[le][j];
        const float4* wr = (const float4*)&sWe[j][d0];
        float4 w0 = wr[0], w1 = wr[1];
        ep[0] = fmaf(a, w0.x, ep[0]); ep[1] = fmaf(a, w0.y, ep[1]);
        ep[2] = fmaf(a, w0.z, ep[2]); ep[3] = fmaf(a, w0.w, ep[3]);
        ep[4] = fmaf(a, w1.x, ep[4]); ep[5] = fmaf(a, w1.y, ep[5]);
        ep[6] = fmaf(a, w1.z, ep[6]); ep[7] = fmaf(a, w1.w, ep[7]);
      }
      const float4* vp = (const float4*)(vmat + (size_t)src * HID + d0);
      float4 v0 = vp[0], v1 = vp[1];
      float* mp = msg + (size_t)dst * HID + d0;
      atomicAdd(mp + 0, expa * (v0.x + ep[0]));
      atomicAdd(mp + 1, expa * (v0.y + ep[1]));
      atomicAdd(mp + 2, expa * (v0.z + ep[2]));
      atomicAdd(mp + 3, expa * (v0.w + ep[3]));
      atomicAdd(mp + 4, expa * (v1.x + ep[4]));
      atomicAdd(mp + 5, expa * (v1.y + ep[5]));
      atomicAdd(mp + 6, expa * (v1.z + ep[6]));
      atomicAdd(mp + 7, expa * (v1.w + ep[7]));
    }
  }
}

extern "C" void kernel_launch(void* const* d_in, const int* in_sizes, int n_in,
                              void* d_out, int out_size, void* d_ws, size_t ws_size,
                              hipStream_t stream) {
  const float* x = (const float*)d_in[0];
  const int* ei = (const int*)d_in[1];
  const float* ea = (const float*)d_in[2];
  const float* Wq = (const float*)d_in[3];
  const float* bq = (const float*)d_in[4];
  const float* Wk = (const float*)d_in[5];
  const float* bk = (const float*)d_in[6];
  const float* Wv = (const float*)d_in[7];
  const float* bv = (const float*)d_in[8];
  const float* We = (const float*)d_in[9];
  const float* be = (const float*)d_in[10];
  const float* Wskip = (const float*)d_in[11];
  const float* bskip = (const float*)d_in[12];
  const float* ln1w = (const float*)d_in[13];
  const float* ln1b = (const float*)d_in[14];
  const float* W1 = (const float*)d_in[15];
  const float* b1 = (const float*)d_in[16];
  const float* W2 = (const float*)d_in[17];
  const float* b2 = (const float*)d_in[18];
  const float* ln2w = (const float*)d_in[19];
  const float* ln2b = (const float*)d_in[20];

  int N = in_sizes[0] / HID;
  int E = in_sizes[1] / 2;
  size_t nf = (size_t)N * HID;

  float* ws = (float*)d_ws;
  size_t off = 0;
  float* h = ws + off; off += nf;
  float* q = ws + off; off += nf;
  float* kbuf = ws + off; off += nf;
  float* vbuf = ws + off; off += nf;
  float* skip = ws + off; off += nf;
  float* x1 = ws + off; off += nf;
  float* h2 = ws + off; off += nf;
  float* alpha = ws + off; off += (size_t)E * NHEADS;
  unsigned* amax = (unsigned*)(ws + off); off += (size_t)N * NHEADS;
  float* denom = ws + off; off += (size_t)N * NHEADS;
  float* msg = ws + off; off += nf;
  float* t = ws;  // aliases h/q/k/v region (N*512 floats), all dead by FFN1

  // zero amax_enc (0 encodes below min-finite), denom, msg (contiguous)
  hipMemsetAsync(amax, 0, ((size_t)N * NHEADS * 2 + nf) * sizeof(float), stream);

  int ln_blocks = (N + 3) / 4;
  ln_kernel<<<ln_blocks, 256, 0, stream>>>(x, h, ln1w, ln1b, N);

  dim3 g1((N + 63) / 64, 1);
  gemm_kernel<128, 0, 0><<<g1, 256, 0, stream>>>(h, Wq, bq, nullptr, q, N, 128);
  gemm_kernel<128, 0, 0><<<g1, 256, 0, stream>>>(h, Wk, bk, nullptr, kbuf, N, 128);
  gemm_kernel<128, 0, 0><<<g1, 256, 0, stream>>>(h, Wv, bv, nullptr, vbuf, N, 128);
  gemm_kernel<128, 0, 0><<<g1, 256, 0, stream>>>(h, Wskip, bskip, nullptr, skip, N, 128);

  edge_pass1<<<4096, 256, 0, stream>>>(ei, ea, We, be, q, kbuf, alpha, amax, E);
  edge_pass2<<<4096, 256, 0, stream>>>(ei, ea, We, be, vbuf, alpha, amax, denom, msg, E);

  finalize1_kernel<<<ln_blocks, 256, 0, stream>>>(x, msg, denom, skip, ln2w, ln2b, x1, h2, N);

  dim3 g2((N + 63) / 64, 4);
  gemm_kernel<128, 1, 0><<<g2, 256, 0, stream>>>(h2, W1, b1, nullptr, t, N, 512);
  dim3 g3((N + 63) / 64, 1);
  gemm_kernel<512, 0, 1><<<g3, 256, 0, stream>>>(t, W2, b2, x1, (float*)d_out, N, 128);
}

// Round 2
// 1230.911 us; speedup vs baseline: 3.0241x; 3.0241x over previous
//
#include <hip/hip_runtime.h>
#include <math.h>

#define HID 128
#define NHEADS 8
#define DH 16
#define EDGE_D 32

// ---------- helpers ----------
static __device__ __forceinline__ float wave_allreduce_sum(float v) {
#pragma unroll
  for (int off = 32; off > 0; off >>= 1) v += __shfl_xor(v, off);
  return v;
}

// ---------- LayerNorm: out = LN(in) ----------
__global__ __launch_bounds__(256) void ln_kernel(const float* __restrict__ in,
                                                 float* __restrict__ out,
                                                 const float* __restrict__ w,
                                                 const float* __restrict__ b, int n) {
  int wpb = blockDim.x >> 6;
  int row0 = blockIdx.x * wpb + (threadIdx.x >> 6);
  int lane = threadIdx.x & 63;
  int stride = gridDim.x * wpb;
  for (int row = row0; row < n; row += stride) {
    const float* p = in + (size_t)row * HID;
    float a = p[lane], c = p[lane + 64];
    float s = wave_allreduce_sum(a + c);
    float s2 = wave_allreduce_sum(a * a + c * c);
    float mean = s * (1.f / 128.f);
    float var = s2 * (1.f / 128.f) - mean * mean;
    float rs = rsqrtf(var + 1e-5f);
    float* o = out + (size_t)row * HID;
    o[lane] = (a - mean) * rs * w[lane] + b[lane];
    o[lane + 64] = (c - mean) * rs * w[lane + 64] + b[lane + 64];
  }
}

// ---------- finalize conv + LN2: x1 = x + msg + skip ; h2 = LN(x1) ----------
// (msg is already divided by denom in fused_edge)
__global__ __launch_bounds__(256) void finalize1_kernel(
    const float* __restrict__ x, const float* __restrict__ msg,
    const float* __restrict__ skip,
    const float* __restrict__ w, const float* __restrict__ b,
    float* __restrict__ x1, float* __restrict__ h2, int n) {
  int wpb = blockDim.x >> 6;
  int row0 = blockIdx.x * wpb + (threadIdx.x >> 6);
  int lane = threadIdx.x & 63;
  int stride = gridDim.x * wpb;
  for (int row = row0; row < n; row += stride) {
    size_t base = (size_t)row * HID;
    float a = x[base + lane] + msg[base + lane] + skip[base + lane];
    float c = x[base + 64 + lane] + msg[base + 64 + lane] + skip[base + 64 + lane];
    x1[base + lane] = a;
    x1[base + 64 + lane] = c;
    float s = wave_allreduce_sum(a + c);
    float s2 = wave_allreduce_sum(a * a + c * c);
    float mean = s * (1.f / 128.f);
    float var = s2 * (1.f / 128.f) - mean * mean;
    float rs = rsqrtf(var + 1e-5f);
    h2[base + lane] = (a - mean) * rs * w[lane] + b[lane];
    h2[base + 64 + lane] = (c - mean) * rs * w[lane + 64] + b[lane + 64];
  }
}

// ---------- generic fp32 GEMM: C = act(A@B + bias) (+D) ----------
template <int K, int ACT, int ADDD>
__global__ __launch_bounds__(256) void gemm_kernel(
    const float* __restrict__ A, const float* __restrict__ B,
    const float* __restrict__ bias, const float* __restrict__ D,
    float* __restrict__ C, int n, int M) {
  __shared__ float As[64][33];
  __shared__ float Bs[32][129];
  int r0 = blockIdx.x * 64;
  int c0 = blockIdx.y * 128;
  int t = threadIdx.x;
  int tx = t & 15, ty = t >> 4;
  float acc[4][8];
#pragma unroll
  for (int i = 0; i < 4; i++)
#pragma unroll
    for (int j = 0; j < 8; j++) acc[i][j] = 0.f;

  for (int kc = 0; kc < K; kc += 32) {
    __syncthreads();
#pragma unroll
    for (int i = 0; i < 8; i++) {
      int idx = i * 256 + t;
      int r = idx >> 5, kk = idx & 31;
      int gr = r0 + r;
      As[r][kk] = (gr < n) ? A[(size_t)gr * K + kc + kk] : 0.f;
    }
#pragma unroll
    for (int i = 0; i < 16; i++) {
      int idx = i * 256 + t;
      int kk = idx >> 7, cc = idx & 127;
      Bs[kk][cc] = B[(size_t)(kc + kk) * M + c0 + cc];
    }
    __syncthreads();
#pragma unroll
    for (int kk = 0; kk < 32; kk++) {
      float av[4], bv[8];
#pragma unroll
      for (int i = 0; i < 4; i++) av[i] = As[ty + 16 * i][kk];
#pragma unroll
      for (int j = 0; j < 8; j++) bv[j] = Bs[kk][tx + 16 * j];
#pragma unroll
      for (int i = 0; i < 4; i++)
#pragma unroll
        for (int j = 0; j < 8; j++) acc[i][j] = fmaf(av[i], bv[j], acc[i][j]);
    }
  }
#pragma unroll
  for (int i = 0; i < 4; i++) {
    int r = r0 + ty + 16 * i;
    if (r < n) {
#pragma unroll
      for (int j = 0; j < 8; j++) {
        int c = c0 + tx + 16 * j;
        float val = acc[i][j] + bias[c];
        if (ACT == 1) val = 0.5f * val * (1.f + erff(val * 0.70710678118f));
        if (ADDD) val += D[(size_t)r * M + c];
        C[(size_t)r * M + c] = val;
      }
    }
  }
}

// ---------- counting sort by dst ----------
__global__ __launch_bounds__(256) void hist_kernel(const int* __restrict__ dstp,
                                                   int* __restrict__ cnt, int E) {
  int i = blockIdx.x * blockDim.x + threadIdx.x;
  int stride = gridDim.x * blockDim.x;
  for (; i < E; i += stride) atomicAdd(&cnt[dstp[i]], 1);
}

__global__ __launch_bounds__(256) void scan_partial(const int* __restrict__ cnt,
                                                    int* __restrict__ bs, int N) {
  __shared__ int sd[256];
  int idx = blockIdx.x * 256 + threadIdx.x;
  sd[threadIdx.x] = (idx < N) ? cnt[idx] : 0;
  __syncthreads();
  for (int s = 128; s > 0; s >>= 1) {
    if (threadIdx.x < s) sd[threadIdx.x] += sd[threadIdx.x + s];
    __syncthreads();
  }
  if (threadIdx.x == 0) bs[blockIdx.x] = sd[0];
}

__global__ __launch_bounds__(256) void scan_bs(const int* __restrict__ bs,
                                               int* __restrict__ bs2, int nb) {
  __shared__ int sd[256];
  int t = threadIdx.x;
  int v = (t < nb) ? bs[t] : 0;
  sd[t] = v;
  __syncthreads();
  for (int s = 1; s < 256; s <<= 1) {
    int add = (t >= s) ? sd[t - s] : 0;
    __syncthreads();
    sd[t] += add;
    __syncthreads();
  }
  bs2[t] = sd[t] - v;  // exclusive
}

__global__ __launch_bounds__(256) void scan_final(const int* __restrict__ cnt,
                                                  const int* __restrict__ bs2,
                                                  int* __restrict__ offs,
                                                  int* __restrict__ woff, int N) {
  __shared__ int sd[256];
  int t = threadIdx.x;
  int idx = blockIdx.x * 256 + t;
  int v = (idx < N) ? cnt[idx] : 0;
  sd[t] = v;
  __syncthreads();
  for (int s = 1; s < 256; s <<= 1) {
    int add = (t >= s) ? sd[t - s] : 0;
    __syncthreads();
    sd[t] += add;
    __syncthreads();
  }
  if (idx < N) {
    int ex = sd[t] - v + bs2[blockIdx.x];
    offs[idx] = ex;
    woff[idx] = ex;
  }
}

__global__ __launch_bounds__(256) void scatter_kernel(const int* __restrict__ ei,
                                                      int* __restrict__ woff,
                                                      int2* __restrict__ sorted,
                                                      int E) {
  int i = blockIdx.x * blockDim.x + threadIdx.x;
  int stride = gridDim.x * blockDim.x;
  for (; i < E; i += stride) {
    int src = ei[i];
    int dst = ei[E + i];
    int pos = atomicAdd(&woff[dst], 1);
    sorted[pos] = make_int2(src, i);
  }
}

// ---------- fused edge attention: one wave per dst node, online softmax ----------
// msg[dst] = sum_e softmax(alpha)_e * (v[src_e] + eproj_e)   (already /denom)
__global__ __launch_bounds__(256) void fused_edge(
    const int* __restrict__ offs, const int* __restrict__ cnt,
    const int2* __restrict__ sorted, const float* __restrict__ ea,
    const float* __restrict__ We, const float* __restrict__ be,
    const float* __restrict__ qmat, const float* __restrict__ kmat,
    const float* __restrict__ vmat, float* __restrict__ msg, int Nn) {
  int lane = threadIdx.x & 63;
  int wv = threadIdx.x >> 6;
  int wstride = gridDim.x * 4;
  // We columns for this lane's two dims, held in VGPRs
  float we0[32], we1[32];
#pragma unroll
  for (int j = 0; j < 32; j++) {
    we0[j] = We[j * HID + lane];
    we1[j] = We[j * HID + lane + 64];
  }
  float be0 = be[lane], be1 = be[lane + 64];

  for (int node = blockIdx.x * 4 + wv; node < Nn; node += wstride) {
    int beg = offs[node], num = cnt[node];
    size_t qb = (size_t)node * HID + lane;
    float q0 = qmat[qb] * 0.25f;       // fold 1/sqrt(16)
    float q1 = qmat[qb + 64] * 0.25f;
    float m1 = -1e30f, m2 = -1e30f, l1 = 0.f, l2 = 0.f, a0 = 0.f, a1 = 0.f;

    float eac = 0.f, k0c = 0.f, k1c = 0.f, v0c = 0.f, v1c = 0.f;
    if (num > 0) {
      int2 sc = sorted[beg];
      eac = ea[(size_t)sc.y * EDGE_D + (lane & 31)];
      size_t sb = (size_t)sc.x * HID + lane;
      k0c = kmat[sb]; k1c = kmat[sb + 64];
      v0c = vmat[sb]; v1c = vmat[sb + 64];
    }
    for (int i = 0; i < num; i++) {
      float ean = 0.f, k0n = 0.f, k1n = 0.f, v0n = 0.f, v1n = 0.f;
      if (i + 1 < num) {  // prefetch next edge (hides gather latency)
        int2 sc = sorted[beg + i + 1];
        ean = ea[(size_t)sc.y * EDGE_D + (lane & 31)];
        size_t sb = (size_t)sc.x * HID + lane;
        k0n = kmat[sb]; k1n = kmat[sb + 64];
        v0n = vmat[sb]; v1n = vmat[sb + 64];
      }
      // edge projection: e = ea @ We + be  (broadcast ea via readlane)
      float e0 = be0, e1 = be1;
#pragma unroll
      for (int j = 0; j < 32; j++) {
        float aj = __shfl(eac, j);
        e0 = fmaf(aj, we0[j], e0);
        e1 = fmaf(aj, we1[j], e1);
      }
      // alpha per head: reduce q*(k+e) within 16-lane groups
      float p0 = q0 * (k0c + e0), p1 = q1 * (k1c + e1);
#pragma unroll
      for (int off = 1; off < 16; off <<= 1) {
        p0 += __shfl_xor(p0, off);
        p1 += __shfl_xor(p1, off);
      }
      // online softmax update
      float nm1 = fmaxf(m1, p0), nm2 = fmaxf(m2, p1);
      float s1 = __expf(m1 - nm1), s2 = __expf(m2 - nm2);
      float w1 = __expf(p0 - nm1), w2 = __expf(p1 - nm2);
      l1 = l1 * s1 + w1;
      l2 = l2 * s2 + w2;
      a0 = a0 * s1 + w1 * (v0c + e0);
      a1 = a1 * s2 + w2 * (v1c + e1);
      m1 = nm1; m2 = nm2;
      eac = ean; k0c = k0n; k1c = k1n; v0c = v0n; v1c = v1n;
    }
    msg[qb] = a0 / (l1 + 1e-16f);
    msg[qb + 64] = a1 / (l2 + 1e-16f);
  }
}

extern "C" void kernel_launch(void* const* d_in, const int* in_sizes, int n_in,
                              void* d_out, int out_size, void* d_ws, size_t ws_size,
                              hipStream_t stream) {
  const float* x = (const float*)d_in[0];
  const int* ei = (const int*)d_in[1];
  const float* ea = (const float*)d_in[2];
  const float* Wq = (const float*)d_in[3];
  const float* bq = (const float*)d_in[4];
  const float* Wk = (const float*)d_in[5];
  const float* bk = (const float*)d_in[6];
  const float* Wv = (const float*)d_in[7];
  const float* bv = (const float*)d_in[8];
  const float* We = (const float*)d_in[9];
  const float* be = (const float*)d_in[10];
  const float* Wskip = (const float*)d_in[11];
  const float* bskip = (const float*)d_in[12];
  const float* ln1w = (const float*)d_in[13];
  const float* ln1b = (const float*)d_in[14];
  const float* W1 = (const float*)d_in[15];
  const float* b1 = (const float*)d_in[16];
  const float* W2 = (const float*)d_in[17];
  const float* b2 = (const float*)d_in[18];
  const float* ln2w = (const float*)d_in[19];
  const float* ln2b = (const float*)d_in[20];

  int N = in_sizes[0] / HID;
  int E = in_sizes[1] / 2;
  size_t nf = (size_t)N * HID;

  float* ws = (float*)d_ws;
  size_t off = 0;
  float* h = ws + off; off += nf;
  float* q = ws + off; off += nf;
  float* kbuf = ws + off; off += nf;
  float* vbuf = ws + off; off += nf;
  float* skip = ws + off; off += nf;
  float* x1 = ws + off; off += nf;
  float* h2 = ws + off; off += nf;
  float* msg = ws + off; off += nf;
  // int region (sorted first for 8B alignment)
  int2* sorted = (int2*)(ws + off); off += (size_t)E * 2;
  int* cnt = (int*)(ws + off); off += N;
  int* offs = (int*)(ws + off); off += N;
  int* woff = (int*)(ws + off); off += N;
  int* bs = (int*)(ws + off); off += 256;
  int* bs2 = (int*)(ws + off); off += 256;
  float* t = ws;  // FFN intermediate aliases h/q/k/v (N*512 floats, dead by then)

  hipMemsetAsync(cnt, 0, (size_t)N * sizeof(int), stream);

  int ln_blocks = (N + 3) / 4;
  ln_kernel<<<ln_blocks, 256, 0, stream>>>(x, h, ln1w, ln1b, N);

  dim3 g1((N + 63) / 64, 1);
  gemm_kernel<128, 0, 0><<<g1, 256, 0, stream>>>(h, Wq, bq, nullptr, q, N, 128);
  gemm_kernel<128, 0, 0><<<g1, 256, 0, stream>>>(h, Wk, bk, nullptr, kbuf, N, 128);
  gemm_kernel<128, 0, 0><<<g1, 256, 0, stream>>>(h, Wv, bv, nullptr, vbuf, N, 128);
  gemm_kernel<128, 0, 0><<<g1, 256, 0, stream>>>(h, Wskip, bskip, nullptr, skip, N, 128);

  // counting sort by dst
  int nb = (N + 255) / 256;
  hist_kernel<<<1024, 256, 0, stream>>>(ei + E, cnt, E);
  scan_partial<<<nb, 256, 0, stream>>>(cnt, bs, N);
  scan_bs<<<1, 256, 0, stream>>>(bs, bs2, nb);
  scan_final<<<nb, 256, 0, stream>>>(cnt, bs2, offs, woff, N);
  scatter_kernel<<<1024, 256, 0, stream>>>(ei, woff, sorted, E);

  fused_edge<<<4096, 256, 0, stream>>>(offs, cnt, sorted, ea, We, be, q, kbuf,
                                       vbuf, msg, N);

  finalize1_kernel<<<ln_blocks, 256, 0, stream>>>(x, msg, skip, ln2w, ln2b, x1, h2, N);

  dim3 g2((N + 63) / 64, 4);
  gemm_kernel<128, 1, 0><<<g2, 256, 0, stream>>>(h2, W1, b1, nullptr, t, N, 512);
  dim3 g3((N + 63) / 64, 1);
  gemm_kernel<512, 0, 1><<<g3, 256, 0, stream>>>(t, W2, b2, x1, (float*)d_out, N, 128);
}

// Round 3
// 646.861 us; speedup vs baseline: 5.7546x; 1.9029x over previous
//
#include <hip/hip_runtime.h>
#include <math.h>

#define HID 128
#define EDGE_D 32
#define SC 0.36067376f  // 0.25 * log2(e)

typedef unsigned short u16;
typedef unsigned int u32;
typedef __bf16 bf16x8 __attribute__((ext_vector_type(8)));
typedef float f32x4 __attribute__((ext_vector_type(4)));
typedef u32 u32x4 __attribute__((ext_vector_type(4)));

static __device__ __forceinline__ u16 f2bf(float f) {
  u32 u = __float_as_uint(f);
  u += 0x7fffu + ((u >> 16) & 1u);
  return (u16)(u >> 16);
}
static __device__ __forceinline__ float bf2f(u16 b) {
  return __uint_as_float(((u32)b) << 16);
}
// all-lanes sum within each 16-lane row via DPP row rotates (pure VALU)
static __device__ __forceinline__ float grp16_sum(float x) {
  x += __int_as_float(__builtin_amdgcn_mov_dpp(__float_as_int(x), 0x128, 0xf, 0xf, true));
  x += __int_as_float(__builtin_amdgcn_mov_dpp(__float_as_int(x), 0x124, 0xf, 0xf, true));
  x += __int_as_float(__builtin_amdgcn_mov_dpp(__float_as_int(x), 0x122, 0xf, 0xf, true));
  x += __int_as_float(__builtin_amdgcn_mov_dpp(__float_as_int(x), 0x121, 0xf, 0xf, true));
  return x;
}
static __device__ __forceinline__ float wave_allreduce_sum(float v) {
#pragma unroll
  for (int off = 32; off > 0; off >>= 1) v += __shfl_xor(v, off);
  return v;
}

// ---------- LayerNorm: out_bf16 = LN(in) ----------
__global__ __launch_bounds__(256) void ln_kernel(const float* __restrict__ in,
                                                 u16* __restrict__ out,
                                                 const float* __restrict__ w,
                                                 const float* __restrict__ b, int n) {
  int row0 = blockIdx.x * 4 + (threadIdx.x >> 6);
  int lane = threadIdx.x & 63;
  int stride = gridDim.x * 4;
  for (int row = row0; row < n; row += stride) {
    const float* p = in + (size_t)row * HID;
    float a = p[lane], c = p[lane + 64];
    float s = wave_allreduce_sum(a + c);
    float s2 = wave_allreduce_sum(a * a + c * c);
    float mean = s * (1.f / 128.f);
    float var = s2 * (1.f / 128.f) - mean * mean;
    float rs = rsqrtf(var + 1e-5f);
    u16* o = out + (size_t)row * HID;
    o[lane] = f2bf((a - mean) * rs * w[lane] + b[lane]);
    o[lane + 64] = f2bf((c - mean) * rs * w[lane + 64] + b[lane + 64]);
  }
}

// ---------- finalize conv + LN2: x1 = x + msg + skip ; h2_bf16 = LN(x1) ----------
__global__ __launch_bounds__(256) void finalize1_kernel(
    const float* __restrict__ x, const float* __restrict__ msg,
    const float* __restrict__ skip, const float* __restrict__ w,
    const float* __restrict__ b, float* __restrict__ x1, u16* __restrict__ h2,
    int n) {
  int row0 = blockIdx.x * 4 + (threadIdx.x >> 6);
  int lane = threadIdx.x & 63;
  int stride = gridDim.x * 4;
  for (int row = row0; row < n; row += stride) {
    size_t base = (size_t)row * HID;
    float a = x[base + lane] + msg[base + lane] + skip[base + lane];
    float c = x[base + 64 + lane] + msg[base + 64 + lane] + skip[base + 64 + lane];
    x1[base + lane] = a;
    x1[base + 64 + lane] = c;
    float s = wave_allreduce_sum(a + c);
    float s2 = wave_allreduce_sum(a * a + c * c);
    float mean = s * (1.f / 128.f);
    float var = s2 * (1.f / 128.f) - mean * mean;
    float rs = rsqrtf(var + 1e-5f);
    h2[base + lane] = f2bf((a - mean) * rs * w[lane] + b[lane]);
    h2[base + 64 + lane] = f2bf((c - mean) * rs * w[lane + 64] + b[lane + 64]);
  }
}

// ---------- weight conversion: f32 -> transposed bf16 [M][K] ----------
__global__ __launch_bounds__(256) void convert_weights(
    const float* __restrict__ Wq, const float* __restrict__ Wk,
    const float* __restrict__ Wv, const float* __restrict__ Ws,
    const float* __restrict__ W1, const float* __restrict__ W2,
    u16* __restrict__ WqkvsT, u16* __restrict__ W1T, u16* __restrict__ W2T) {
  int idx = blockIdx.x * 256 + threadIdx.x;
  if (idx < 65536) {
    int m = idx >> 7, k = idx & 127;
    const float* Wm = m < 128 ? Wq : m < 256 ? Wk : m < 384 ? Wv : Ws;
    WqkvsT[idx] = f2bf(Wm[k * 128 + (m & 127)]);
  } else if (idx < 131072) {
    int j = idx - 65536;
    int m = j >> 7, k = j & 127;
    W1T[j] = f2bf(W1[k * 512 + m]);
  } else if (idx < 196608) {
    int j = idx - 131072;
    int m = j >> 9, k = j & 511;
    W2T[j] = f2bf(W2[k * 128 + m]);
  }
}

// ---------- bf16 MFMA GEMM: tile 128x128, 4 waves, 16x16x32 ----------
// A [n][K] bf16, Bt [M][K] bf16 (B transposed). EPI: 0=QKVS split, 1=GELU->bf16, 2=+bias+add->f32
template <int EPI>
__global__ __launch_bounds__(256) void gemm_bf16(
    const u16* __restrict__ A, const u16* __restrict__ Bt, int n, int K,
    const float* __restrict__ bias0, const float* __restrict__ bias1,
    const float* __restrict__ bias2, const float* __restrict__ bias3,
    float* __restrict__ of0, u16* __restrict__ ob1, u16* __restrict__ ob2,
    float* __restrict__ of3, const float* __restrict__ addsrc) {
  __shared__ u16 As[128 * 32];
  __shared__ u16 Bs[128 * 32];
  int t = threadIdx.x;
  int w = t >> 6, lane = t & 63;
  int g = lane >> 4, sr = lane & 15;
  int r0 = blockIdx.x * 128;
  int c0 = blockIdx.y * 128;
  f32x4 acc[2][8];
#pragma unroll
  for (int m = 0; m < 2; m++)
#pragma unroll
    for (int nn = 0; nn < 8; nn++) acc[m][nn] = {0.f, 0.f, 0.f, 0.f};

  for (int kc = 0; kc < K; kc += 32) {
    __syncthreads();
#pragma unroll
    for (int i = 0; i < 2; i++) {
      int idx = i * 256 + t;  // 0..511 : row = idx>>2, 16B chunk = idx&3
      int row = idx >> 2, c4 = idx & 3;
      u32x4 va = *(const u32x4*)(A + (size_t)(r0 + row) * K + kc + c4 * 8);
      *(u32x4*)&As[idx * 8] = va;
      u32x4 vb = *(const u32x4*)(Bt + (size_t)(c0 + row) * K + kc + c4 * 8);
      *(u32x4*)&Bs[idx * 8] = vb;
    }
    __syncthreads();
    bf16x8 a0 = *(const bf16x8*)&As[(w * 32 + sr) * 32 + g * 8];
    bf16x8 a1 = *(const bf16x8*)&As[(w * 32 + 16 + sr) * 32 + g * 8];
#pragma unroll
    for (int nn = 0; nn < 8; nn++) {
      bf16x8 b = *(const bf16x8*)&Bs[(nn * 16 + sr) * 32 + g * 8];
      acc[0][nn] = __builtin_amdgcn_mfma_f32_16x16x32_bf16(a0, b, acc[0][nn], 0, 0, 0);
      acc[1][nn] = __builtin_amdgcn_mfma_f32_16x16x32_bf16(a1, b, acc[1][nn], 0, 0, 0);
    }
  }
#pragma unroll
  for (int m = 0; m < 2; m++) {
#pragma unroll
    for (int nn = 0; nn < 8; nn++) {
#pragma unroll
      for (int j = 0; j < 4; j++) {
        int row = r0 + w * 32 + m * 16 + g * 4 + j;
        if (row < n) {
          int cj = nn * 16 + sr;
          float val = acc[m][nn][j];
          if (EPI == 0) {
            int cb = blockIdx.y;
            const float* bp = cb == 0 ? bias0 : cb == 1 ? bias1 : cb == 2 ? bias2 : bias3;
            float v2 = val + bp[cj];
            size_t o = (size_t)row * HID + cj;
            if (cb == 0) of0[o] = v2;
            else if (cb == 1) ob1[o] = f2bf(v2);
            else if (cb == 2) ob2[o] = f2bf(v2);
            else of3[o] = v2;
          } else if (EPI == 1) {
            int cjg = blockIdx.y * 128 + cj;
            float v2 = val + bias0[cjg];
            v2 = 0.5f * v2 * (1.f + erff(v2 * 0.70710678118f));
            ob1[(size_t)row * 512 + cjg] = f2bf(v2);
          } else {
            float v2 = val + bias0[cj] + addsrc[(size_t)row * HID + cj];
            of0[(size_t)row * HID + cj] = v2;
          }
        }
      }
    }
  }
}

// ---------- counting sort by dst ----------
__global__ __launch_bounds__(256) void hist_kernel(const int* __restrict__ dstp,
                                                   int* __restrict__ cnt, int E) {
  int i = blockIdx.x * blockDim.x + threadIdx.x;
  int stride = gridDim.x * blockDim.x;
  for (; i < E; i += stride) atomicAdd(&cnt[dstp[i]], 1);
}

__global__ __launch_bounds__(256) void scan_partial(const int* __restrict__ cnt,
                                                    int* __restrict__ bs, int N) {
  __shared__ int sd[256];
  int idx = blockIdx.x * 256 + threadIdx.x;
  sd[threadIdx.x] = (idx < N) ? cnt[idx] : 0;
  __syncthreads();
  for (int s = 128; s > 0; s >>= 1) {
    if (threadIdx.x < s) sd[threadIdx.x] += sd[threadIdx.x + s];
    __syncthreads();
  }
  if (threadIdx.x == 0) bs[blockIdx.x] = sd[0];
}

__global__ __launch_bounds__(256) void scan_bs(const int* __restrict__ bs,
                                               int* __restrict__ bs2, int nb) {
  __shared__ int sd[256];
  int t = threadIdx.x;
  int v = (t < nb) ? bs[t] : 0;
  sd[t] = v;
  __syncthreads();
  for (int s = 1; s < 256; s <<= 1) {
    int add = (t >= s) ? sd[t - s] : 0;
    __syncthreads();
    sd[t] += add;
    __syncthreads();
  }
  bs2[t] = sd[t] - v;  // exclusive
}

__global__ __launch_bounds__(256) void scan_final(const int* __restrict__ cnt,
                                                  const int* __restrict__ bs2,
                                                  int* __restrict__ offs,
                                                  int* __restrict__ woff, int N) {
  __shared__ int sd[256];
  int t = threadIdx.x;
  int idx = blockIdx.x * 256 + t;
  int v = (idx < N) ? cnt[idx] : 0;
  sd[t] = v;
  __syncthreads();
  for (int s = 1; s < 256; s <<= 1) {
    int add = (t >= s) ? sd[t - s] : 0;
    __syncthreads();
    sd[t] += add;
    __syncthreads();
  }
  if (idx < N) {
    int ex = sd[t] - v + bs2[blockIdx.x];
    offs[idx] = ex;
    woff[idx] = ex;
  }
}

__global__ __launch_bounds__(256) void scatter_kernel(const int* __restrict__ ei,
                                                      int* __restrict__ woff,
                                                      int* __restrict__ srcs,
                                                      int* __restrict__ eids, int E) {
  int i = blockIdx.x * blockDim.x + threadIdx.x;
  int stride = gridDim.x * blockDim.x;
  for (; i < E; i += stride) {
    int src = ei[i];
    int dst = ei[E + i];
    int pos = atomicAdd(&woff[dst], 1);
    srcs[pos] = src;
    eids[pos] = i;
  }
}

// ---------- qWe precompute: qwe[node][h][32] = SC * sum_{d in h} q_d We[j][d]; qbe[node][h] ----------
__global__ __launch_bounds__(256) void qwe_kernel(const float* __restrict__ q,
                                                  const float* __restrict__ We,
                                                  const float* __restrict__ be,
                                                  float* __restrict__ qwe,
                                                  float* __restrict__ qbe, int Nn) {
  __shared__ float sWe[32][129];
  __shared__ float sbe[128];
  int t = threadIdx.x;
  for (int i = t; i < 32 * 128; i += 256) sWe[i >> 7][i & 127] = We[i];
  if (t < 128) sbe[t] = be[t];
  __syncthreads();
  int lane = t & 63, w = t >> 6;
  int g = lane >> 4, sr = lane & 15;
  int node = blockIdx.x * 4 + w;
  if (node >= Nn) return;
  float q0 = q[(size_t)node * HID + lane];
  float q1 = q[(size_t)node * HID + lane + 64];
  float o00 = 0.f, o01 = 0.f, o10 = 0.f, o11 = 0.f;
  int base = lane & 48;
#pragma unroll
  for (int d0 = 0; d0 < 16; d0++) {
    float qa = __shfl(q0, base + d0);
    float qb = __shfl(q1, base + d0);
    int col = base + d0;  // 16g + d0
    o00 += qa * sWe[2 * sr][col];
    o01 += qa * sWe[2 * sr + 1][col];
    o10 += qb * sWe[2 * sr][64 + col];
    o11 += qb * sWe[2 * sr + 1][64 + col];
  }
  float* qwn = qwe + (size_t)node * 256;
  qwn[g * 32 + 2 * sr] = o00 * SC;
  qwn[g * 32 + 2 * sr + 1] = o01 * SC;
  qwn[(4 + g) * 32 + 2 * sr] = o10 * SC;
  qwn[(4 + g) * 32 + 2 * sr + 1] = o11 * SC;
  float t0 = grp16_sum(q0 * sbe[lane]);
  float t1 = grp16_sum(q1 * sbe[lane + 64]);
  if (sr == 0) {
    qbe[node * 8 + g] = t0 * SC;
    qbe[node * 8 + 4 + g] = t1 * SC;
  }
}

// ---------- fused edge attention: 1 wave/node, online softmax in exp2 domain,
// e handled linearly: alpha += ea.qWe + qbe ; msg_e_part = (sum_e w_e ea_e) @ We ----------
__global__ __launch_bounds__(256) void fused_edge(
    const int* __restrict__ offs, const int* __restrict__ cnt,
    const int* __restrict__ srcs, const int* __restrict__ eids,
    const float* __restrict__ ea, const float* __restrict__ We,
    const float* __restrict__ be, const float* __restrict__ q,
    const u16* __restrict__ kbf, const u16* __restrict__ vbf,
    const float* __restrict__ qwe, const float* __restrict__ qbe,
    float* __restrict__ msg, int Nn) {
  int lane = threadIdx.x & 63;
  int w = threadIdx.x >> 6;
  int g = lane >> 4, sr = lane & 15;
  int wid = blockIdx.x * 4 + w;
  int nw = gridDim.x * 4;
  int per = (Nn + nw - 1) / nw;
  int n0 = wid * per;
  int n1 = min(Nn, n0 + per);
  if (n0 >= n1) return;

  float we0[32], we1[32];
#pragma unroll
  for (int j = 0; j < 32; j++) {
    we0[j] = We[j * HID + lane];
    we1[j] = We[j * HID + lane + 64];
  }
  float be0 = be[lane], be1 = be[lane + 64];

  for (int node = n0; node < n1; node++) {
    int beg = offs[node], num = cnt[node];
    size_t qb_ = (size_t)node * HID + lane;
    if (num == 0) {
      msg[qb_] = 0.f;
      msg[qb_ + 64] = 0.f;
      continue;
    }
    float q0 = q[qb_] * SC, q1 = q[qb_ + 64] * SC;
    const float* qwn = qwe + (size_t)node * 256;
    float2 qw0 = *(const float2*)(qwn + g * 32 + 2 * sr);
    float2 qw1 = *(const float2*)(qwn + (4 + g) * 32 + 2 * sr);
    float qb0 = qbe[node * 8 + g], qb1 = qbe[node * 8 + 4 + g];

    float m1 = -3.0e38f, m2 = -3.0e38f, l1 = 0.f, l2 = 0.f, a0 = 0.f, a1 = 0.f;
    float wa00 = 0.f, wa01 = 0.f, wa10 = 0.f, wa11 = 0.f;

    int sc0 = srcs[beg], eid = eids[beg];
    u16 k0c = kbf[(size_t)sc0 * HID + lane], k1c = kbf[(size_t)sc0 * HID + lane + 64];
    u16 v0c = vbf[(size_t)sc0 * HID + lane], v1c = vbf[(size_t)sc0 * HID + lane + 64];
    float2 eac = *(const float2*)(ea + (size_t)eid * EDGE_D + 2 * sr);

    for (int i = 0; i < num; i++) {
      u16 k0n = 0, k1n = 0, v0n = 0, v1n = 0;
      float2 ean = make_float2(0.f, 0.f);
      if (i + 1 < num) {  // prefetch next edge
        int sn = srcs[beg + i + 1], en = eids[beg + i + 1];
        k0n = kbf[(size_t)sn * HID + lane];
        k1n = kbf[(size_t)sn * HID + lane + 64];
        v0n = vbf[(size_t)sn * HID + lane];
        v1n = vbf[(size_t)sn * HID + lane + 64];
        ean = *(const float2*)(ea + (size_t)en * EDGE_D + 2 * sr);
      }
      float k0 = bf2f(k0c), k1 = bf2f(k1c), v0 = bf2f(v0c), v1 = bf2f(v1c);
      float p0 = fmaf(q0, k0, fmaf(qw0.x, eac.x, qw0.y * eac.y));
      float p1 = fmaf(q1, k1, fmaf(qw1.x, eac.x, qw1.y * eac.y));
      p0 = grp16_sum(p0) + qb0;
      p1 = grp16_sum(p1) + qb1;
      float nm1 = fmaxf(m1, p0), nm2 = fmaxf(m2, p1);
      float s1 = exp2f(m1 - nm1), s2 = exp2f(m2 - nm2);
      float w1 = exp2f(p0 - nm1), w2 = exp2f(p1 - nm2);
      l1 = fmaf(l1, s1, w1);
      l2 = fmaf(l2, s2, w2);
      a0 = fmaf(a0, s1, w1 * v0);
      a1 = fmaf(a1, s2, w2 * v1);
      wa00 = fmaf(wa00, s1, w1 * eac.x);
      wa01 = fmaf(wa01, s1, w1 * eac.y);
      wa10 = fmaf(wa10, s2, w2 * eac.x);
      wa11 = fmaf(wa11, s2, w2 * eac.y);
      m1 = nm1;
      m2 = nm2;
      k0c = k0n; k1c = k1n; v0c = v0n; v1c = v1n; eac = ean;
    }
    // recombine e-part once per node: msg_d += sum_j We[j][d] * wea[h(d)][j] + be_d*l
    float acc0 = be0 * l1, acc1 = be1 * l2;
    int base = lane & 48;
#pragma unroll
    for (int jj = 0; jj < 16; jj++) {
      float wa = __shfl(wa00, base + jj);
      float wb = __shfl(wa01, base + jj);
      acc0 += we0[2 * jj] * wa + we0[2 * jj + 1] * wb;
      float wc = __shfl(wa10, base + jj);
      float wd = __shfl(wa11, base + jj);
      acc1 += we1[2 * jj] * wc + we1[2 * jj + 1] * wd;
    }
    msg[qb_] = (a0 + acc0) / (l1 + 1e-16f);
    msg[qb_ + 64] = (a1 + acc1) / (l2 + 1e-16f);
  }
}

extern "C" void kernel_launch(void* const* d_in, const int* in_sizes, int n_in,
                              void* d_out, int out_size, void* d_ws, size_t ws_size,
                              hipStream_t stream) {
  const float* x = (const float*)d_in[0];
  const int* ei = (const int*)d_in[1];
  const float* ea = (const float*)d_in[2];
  const float* Wq = (const float*)d_in[3];
  const float* bq = (const float*)d_in[4];
  const float* Wk = (const float*)d_in[5];
  const float* bk = (const float*)d_in[6];
  const float* Wv = (const float*)d_in[7];
  const float* bv = (const float*)d_in[8];
  const float* We = (const float*)d_in[9];
  const float* be = (const float*)d_in[10];
  const float* Wskip = (const float*)d_in[11];
  const float* bskip = (const float*)d_in[12];
  const float* ln1w = (const float*)d_in[13];
  const float* ln1b = (const float*)d_in[14];
  const float* W1 = (const float*)d_in[15];
  const float* b1p = (const float*)d_in[16];
  const float* W2 = (const float*)d_in[17];
  const float* b2p = (const float*)d_in[18];
  const float* ln2w = (const float*)d_in[19];
  const float* ln2b = (const float*)d_in[20];

  int N = in_sizes[0] / HID;
  int E = in_sizes[1] / 2;
  size_t nf = (size_t)N * HID;

  float* ws = (float*)d_ws;
  size_t off = 0;
  u16* h_bf = (u16*)(ws + off); off += nf / 2;
  float* q = ws + off; off += nf;
  u16* kbf = (u16*)(ws + off); off += nf / 2;
  u16* vbf = (u16*)(ws + off); off += nf / 2;
  float* skip = ws + off; off += nf;
  float* x1 = ws + off; off += nf;
  u16* h2bf = (u16*)(ws + off); off += nf / 2;
  float* msg = ws + off; off += nf;
  float* qwe = ws + off; off += (size_t)N * 256;  // aliased by t (N*512 bf16) later
  float* qbe = ws + off; off += (size_t)N * 8;
  int* srcs = (int*)(ws + off); off += E;
  int* eids = (int*)(ws + off); off += E;
  int* cnt = (int*)(ws + off); off += N;
  int* offs = (int*)(ws + off); off += N;
  int* woff = (int*)(ws + off); off += N;
  int* bs = (int*)(ws + off); off += 256;
  int* bs2 = (int*)(ws + off); off += 256;
  u16* WqkvsT = (u16*)(ws + off); off += 32768;
  u16* W1T = (u16*)(ws + off); off += 32768;
  u16* W2T = (u16*)(ws + off); off += 32768;
  u16* tbf = (u16*)qwe;  // FFN intermediate aliases qwe (dead after fused_edge)

  hipMemsetAsync(cnt, 0, (size_t)N * sizeof(int), stream);
  convert_weights<<<768, 256, 0, stream>>>(Wq, Wk, Wv, Wskip, W1, W2, WqkvsT, W1T, W2T);

  int ln_blocks = (N + 3) / 4;
  ln_kernel<<<ln_blocks, 256, 0, stream>>>(x, h_bf, ln1w, ln1b, N);

  dim3 gq((N + 127) / 128, 4);
  gemm_bf16<0><<<gq, 256, 0, stream>>>(h_bf, WqkvsT, N, 128, bq, bk, bv, bskip,
                                       q, kbf, vbf, skip, nullptr);

  int nb = (N + 255) / 256;
  hist_kernel<<<1024, 256, 0, stream>>>(ei + E, cnt, E);
  scan_partial<<<nb, 256, 0, stream>>>(cnt, bs, N);
  scan_bs<<<1, 256, 0, stream>>>(bs, bs2, nb);
  scan_final<<<nb, 256, 0, stream>>>(cnt, bs2, offs, woff, N);
  scatter_kernel<<<1024, 256, 0, stream>>>(ei, woff, srcs, eids, E);

  qwe_kernel<<<(N + 3) / 4, 256, 0, stream>>>(q, We, be, qwe, qbe, N);

  fused_edge<<<4096, 256, 0, stream>>>(offs, cnt, srcs, eids, ea, We, be, q,
                                       kbf, vbf, qwe, qbe, msg, N);

  finalize1_kernel<<<ln_blocks, 256, 0, stream>>>(x, msg, skip, ln2w, ln2b, x1, h2bf, N);

  dim3 gf1((N + 127) / 128, 4);
  gemm_bf16<1><<<gf1, 256, 0, stream>>>(h2bf, W1T, N, 128, b1p, nullptr, nullptr,
                                        nullptr, nullptr, tbf, nullptr, nullptr, nullptr);
  dim3 gf2((N + 127) / 128, 1);
  gemm_bf16<2><<<gf2, 256, 0, stream>>>(tbf, W2T, N, 512, b2p, nullptr, nullptr,
                                        nullptr, (float*)d_out, nullptr, nullptr,
                                        nullptr, x1);
}